// Round 6
// baseline (400.741 us; speedup 1.0000x reference)
//
#include <hip/hip_runtime.h>

// CapsClass2d dynamic routing — K=16 MFMA + atomic-free partial reduction.
// b=256, P=1152, C=10, os=is=16, 3 iterations.
// logits telescope: logits_k = dot(sum_{j<k} v_j, votes) -> only vsum state.
//
// R5 lesson: 2.95M device-scope atomicAdds into sbuf ping-ponged L2 lines
// across 8 XCDs (FETCH 95MB + WRITE 118MB per dispatch). R6: each block
// writes a private partial region; squash sums the 72 chunk-partials.
//
// votes[p] = W_p[160x16] @ X_p[16x256] via mfma_f32_16x16x16_bf16:
//   A[m=o][k]: m=lane&15, k=(lane>>4)*4+j ; B[k][n=b]: n=lane&15
//   C/D: col(b)=lane&15, row(o)=(lane>>4)*4+reg
// Grid 72 x 16 (72 % 8 == 0 -> all 16 bt-blocks of a p-chunk land on one XCD
// under round-robin dispatch, so A-frag reuse stays in one L2).
// it=0: coup==0.1 exactly -> MFMA accumulator chains over p.

#define NPOS 1152
#define NC 10
#define IS 16
#define NB 256
#define CO 160
#define CAPS_EPS 1e-8f
#define PW 4
#define PCH 72                      // p-chunks (16 positions each)
#define NA_SLOTS (NPOS * NC * 64)   // 737280 uint2 A-frag slots
#define NB_SLOTS (NPOS * 16 * 64)   // 1179648 uint2 B-frag slots
#define VS_STRIDE 164
#define SM_STRIDE 161
#define PARTREG (16 * CO)           // 2560 floats per (pcid,bt) partial region

typedef __attribute__((ext_vector_type(4))) short bf16x4;
typedef __attribute__((ext_vector_type(8))) short bf16x8;
typedef __attribute__((ext_vector_type(4))) float floatx4;

#if defined(__has_builtin)
#  if __has_builtin(__builtin_amdgcn_mfma_f32_16x16x16bf16_1k)
#    define HAVE_MFMA16 1
#  endif
#endif

__device__ __forceinline__ unsigned f2bf(float x) {
    union { float f; unsigned u; } v; v.f = x;
    return (v.u + 0x7FFFu + ((v.u >> 16) & 1u)) >> 16;
}
__device__ __forceinline__ uint2 pack4(float4 a) {
    uint2 r;
    r.x = f2bf(a.x) | (f2bf(a.y) << 16);
    r.y = f2bf(a.z) | (f2bf(a.w) << 16);
    return r;
}

// Pre-convert W and poses into bf16 K=16 fragment-layout buffers (uint2/lane).
__global__ __launch_bounds__(256) void preconv_kernel(
    const float* __restrict__ poses, const float* __restrict__ weight,
    uint2* __restrict__ wsA, uint2* __restrict__ wsB)
{
    const int gid = blockIdx.x * 256 + threadIdx.x;
    if (gid < NA_SLOTS) {
        const int L = gid & 63, pc = gid >> 6;        // pc = p*10+c
        const int o = L & 15, q = L >> 4;
        const float4 w = *(const float4*)(weight + (size_t)pc * 256 + o * 16 + q * 4);
        wsA[gid] = pack4(w);
    } else {
        const int s = gid - NA_SLOTS;
        if (s < NB_SLOTS) {
            const int L = s & 63, pb = s >> 6;        // pb = p*16+bt
            const int bt = pb & 15, p = pb >> 4;
            const int bl = L & 15, q = L >> 4;
            const float4 x = *(const float4*)(poses +
                ((size_t)(bt * 16 + bl) * NPOS + p) * IS + q * 4);
            wsB[s] = pack4(x);
        }
    }
}

#ifdef HAVE_MFMA16
typedef bf16x4 FragT;
#define MFMA_OP(a, b, c) __builtin_amdgcn_mfma_f32_16x16x16bf16_1k(a, b, c, 0, 0, 0)

__device__ __forceinline__ FragT u2frag(uint2 u) {
    union { uint2 u; FragT f; } c; c.u = u; return c.f;
}
template <bool PC>
__device__ __forceinline__ FragT loadA(const uint2* wsA, const float* weight,
                                       int p, int c, int lane) {
    if (PC) return u2frag(wsA[((size_t)p * NC + c) * 64 + lane]);
    const int o = lane & 15, q = lane >> 4;
    const float4 w = *(const float4*)(weight + ((size_t)p * NC + c) * 256 + o * 16 + q * 4);
    return u2frag(pack4(w));
}
template <bool PC>
__device__ __forceinline__ FragT loadB(const uint2* wsB, const float* poses,
                                       int p, int bt, int lane) {
    if (PC) return u2frag(wsB[((size_t)p * 16 + bt) * 64 + lane]);
    const int bl = lane & 15, q = lane >> 4;
    const float4 x = *(const float4*)(poses +
        ((size_t)(bt * 16 + bl) * NPOS + p) * IS + q * 4);
    return u2frag(pack4(x));
}
#else
// Fallback: K=32 MFMA with zero upper quads, composed from the same buffers.
typedef bf16x8 FragT;
#define MFMA_OP(a, b, c) __builtin_amdgcn_mfma_f32_16x16x32_bf16(a, b, c, 0, 0, 0)

template <bool PC>
__device__ __forceinline__ FragT loadA(const uint2* wsA, const float* weight,
                                       int p, int c, int lane) {
    union { unsigned u[4]; FragT f; } r;
    const bool act = lane < 32;
    const int o = lane & 15, q = (lane >> 4) & 1;
    if (PC) {
        const uint2* base = wsA + ((size_t)p * NC + c) * 64 + q * 32 + o;
        const uint2 lo = base[0], hi = base[16];
        r.u[0] = act ? lo.x : 0u; r.u[1] = act ? lo.y : 0u;
        r.u[2] = act ? hi.x : 0u; r.u[3] = act ? hi.y : 0u;
    } else {
        const float4* s = (const float4*)(weight + ((size_t)p * NC + c) * 256 + o * 16 + q * 8);
        const uint2 lo = pack4(s[0]), hi = pack4(s[1]);
        r.u[0] = act ? lo.x : 0u; r.u[1] = act ? lo.y : 0u;
        r.u[2] = act ? hi.x : 0u; r.u[3] = act ? hi.y : 0u;
    }
    return r.f;
}
template <bool PC>
__device__ __forceinline__ FragT loadB(const uint2* wsB, const float* poses,
                                       int p, int bt, int lane) {
    union { unsigned u[4]; FragT f; } r;
    const bool act = lane < 32;
    const int bl = lane & 15, q = (lane >> 4) & 1;
    if (PC) {
        const uint2* base = wsB + ((size_t)p * 16 + bt) * 64 + q * 32 + bl;
        const uint2 lo = base[0], hi = base[16];
        r.u[0] = act ? lo.x : 0u; r.u[1] = act ? lo.y : 0u;
        r.u[2] = act ? hi.x : 0u; r.u[3] = act ? hi.y : 0u;
    } else {
        const float4* s = (const float4*)(poses +
            ((size_t)(bt * 16 + bl) * NPOS + p) * IS + q * 8);
        const uint2 lo = pack4(s[0]), hi = pack4(s[1]);
        r.u[0] = act ? lo.x : 0u; r.u[1] = act ? lo.y : 0u;
        r.u[2] = act ? hi.x : 0u; r.u[3] = act ? hi.y : 0u;
    }
    return r.f;
}
#endif

template <bool PC, int MODE>   // MODE: 0 = it0, 1 = it1, 2 = it2 (writes coup)
__global__ __launch_bounds__(256, 4) void caps_votes(
    const float* __restrict__ poses, const float* __restrict__ weight,
    const uint2* __restrict__ wsA, const uint2* __restrict__ wsB,
    const float* __restrict__ vsum, float* __restrict__ part,
    float* __restrict__ out_coup)
{
    const int t    = threadIdx.x;
    const int wave = t >> 6, lane = t & 63;
    const int bcol = lane & 15, quad = lane >> 4;
    const int bt   = blockIdx.y, b0 = bt * 16;
    const int pbase = blockIdx.x * (4 * PW) + wave * PW;

    __shared__ float sh_vsum[16 * VS_STRIDE];
    __shared__ float s_merge[16 * SM_STRIDE];
    for (int k = t; k < 16 * SM_STRIDE; k += 256) s_merge[k] = 0.f;
    if (MODE > 0) {
        for (int k = t; k < 16 * CO; k += 256) {
            const int b = k / CO, j = k - b * CO;
            sh_vsum[b * VS_STRIDE + j] = vsum[(size_t)(b0 + b) * CO + j];
        }
    }
    __syncthreads();

    floatx4 sacc[NC];
#pragma unroll
    for (int c = 0; c < NC; ++c) sacc[c] = (floatx4)(0.f);

    for (int pi = 0; pi < PW; ++pi) {
        const int p = pbase + pi;
        const FragT bf = loadB<PC>(wsB, poses, p, bt, lane);

        if (MODE == 0) {
            // coup == 0.1 exactly -> accumulate votes straight into MFMA C
#pragma unroll
            for (int c = 0; c < NC; ++c)
                sacc[c] = MFMA_OP(loadA<PC>(wsA, weight, p, c, lane), bf, sacc[c]);
        } else {
            floatx4 acc[NC];
#pragma unroll
            for (int c = 0; c < NC; ++c)
                acc[c] = MFMA_OP(loadA<PC>(wsA, weight, p, c, lane), bf, (floatx4)(0.f));

            float lg[NC];
            float mx = -1e30f;
#pragma unroll
            for (int c = 0; c < NC; ++c) {
                const float4 vv = *(const float4*)&sh_vsum[bcol * VS_STRIDE + c * 16 + quad * 4];
                float pt = vv.x * acc[c][0] + vv.y * acc[c][1]
                         + vv.z * acc[c][2] + vv.w * acc[c][3];
                pt += __shfl_xor(pt, 16);
                pt += __shfl_xor(pt, 32);
                lg[c] = pt;
                mx = fmaxf(mx, pt);
            }
            float coup[NC], sum = 0.f;
#pragma unroll
            for (int c = 0; c < NC; ++c) { coup[c] = __expf(lg[c] - mx); sum += coup[c]; }
            const float inv = 1.f / sum;
#pragma unroll
            for (int c = 0; c < NC; ++c) coup[c] *= inv;

            if (MODE == 2 && quad == 0) {
                float* cp = out_coup + (size_t)(b0 + bcol) * (NC * NPOS) + p;
#pragma unroll
                for (int c = 0; c < NC; ++c) cp[c * NPOS] = coup[c];
            }

#pragma unroll
            for (int c = 0; c < NC; ++c)
#pragma unroll
                for (int r = 0; r < 4; ++r) sacc[c][r] += coup[c] * acc[c][r];
        }
    }

    // merge block's 4 waves in LDS, then plain coalesced store to this
    // block's PRIVATE partial region (no global atomics — the R5 killer)
    const float scale = (MODE == 0) ? 0.1f : 1.f;
#pragma unroll
    for (int c = 0; c < NC; ++c)
#pragma unroll
        for (int r = 0; r < 4; ++r)
            atomicAdd(&s_merge[bcol * SM_STRIDE + c * 16 + quad * 4 + r], scale * sacc[c][r]);
    __syncthreads();
    float* dst = part + ((size_t)blockIdx.x * 16 + bt) * PARTREG;
    for (int k = t; k < PARTREG; k += 256) {
        const int b = k / CO, j = k - b * CO;
        dst[k] = s_merge[b * SM_STRIDE + j];
    }
}

// Sum the 72 chunk-partials, add bias, squash, update vsum / outputs.
__global__ __launch_bounds__(256) void caps_squash(
    const float* __restrict__ rbias,   // [10, 16]
    const float* __restrict__ part,    // [72][16][16*160]
    float* __restrict__ vsum,          // [256, 10, 16]
    float* __restrict__ out_poses,     // [256, 10, 16]
    float* __restrict__ out_act,       // [256, 10]
    int it)
{
    const int b = blockIdx.x;          // 0..255
    const int t = threadIdx.x;
    if (t >= CO) return;
    const int c = t >> 4;
    const int bt = b >> 4, bl = b & 15;

    float s = rbias[t];
    const float* src = part + (size_t)bt * PARTREG + bl * CO + t;
#pragma unroll 8
    for (int pc = 0; pc < PCH; ++pc)
        s += src[(size_t)pc * 16 * PARTREG];

    float sq = s * s;
    sq += __shfl_xor(sq, 1);
    sq += __shfl_xor(sq, 2);
    sq += __shfl_xor(sq, 4);
    sq += __shfl_xor(sq, 8);
    const float f = (sq / (1.f + sq)) * rsqrtf(sq + CAPS_EPS);
    const float v = f * s;

    const size_t idx = (size_t)b * CO + t;
    if (it == 0) {
        vsum[idx] = v;                 // first write — no memset needed
    } else if (it == 1) {
        vsum[idx] += v;
    } else {
        out_poses[idx] = v;
        if ((t & 15) == 0) out_act[(size_t)b * NC + c] = sqrtf(f * f * sq + CAPS_EPS);
    }
}

extern "C" void kernel_launch(void* const* d_in, const int* in_sizes, int n_in,
                              void* d_out, int out_size, void* d_ws, size_t ws_size,
                              hipStream_t stream) {
    const float* poses  = (const float*)d_in[0];
    // d_in[1] (input_caps_activations) unused by the reference computation.
    const float* weight = (const float*)d_in[2];
    const float* rbias  = (const float*)d_in[3];

    float* out       = (float*)d_out;
    float* out_poses = out;                                   // 256*10*16
    float* out_act   = out + (size_t)NB * CO;                 // 256*10
    float* out_coup  = out_act + (size_t)NB * NC;             // 256*10*1152

    float* vsum = (float*)d_ws;                               // 256*160 floats
    float* part = vsum + (size_t)NB * CO;                     // 72*16*2560 floats
    uint2* wsA  = (uint2*)(part + (size_t)PCH * 16 * PARTREG);
    uint2* wsB  = wsA + NA_SLOTS;

    const size_t need_min  = (size_t)NB * CO * sizeof(float)
                           + (size_t)PCH * 16 * PARTREG * sizeof(float);
    const size_t need_full = need_min + (size_t)(NA_SLOTS + NB_SLOTS) * sizeof(uint2);
    const bool pc = (ws_size >= need_full);
    (void)need_min;   // evidence from R4/R5: ws_size >= 15.7 MB, so >= need_min

    const dim3 vgrid(PCH, 16), vblk(256);
    if (pc) {
        hipLaunchKernelGGL(preconv_kernel,
                           dim3((NA_SLOTS + NB_SLOTS) / 256), dim3(256), 0, stream,
                           poses, weight, wsA, wsB);
        hipLaunchKernelGGL((caps_votes<true, 0>), vgrid, vblk, 0, stream,
                           poses, weight, wsA, wsB, vsum, part, out_coup);
        hipLaunchKernelGGL(caps_squash, dim3(NB), dim3(256), 0, stream,
                           rbias, part, vsum, out_poses, out_act, 0);
        hipLaunchKernelGGL((caps_votes<true, 1>), vgrid, vblk, 0, stream,
                           poses, weight, wsA, wsB, vsum, part, out_coup);
        hipLaunchKernelGGL(caps_squash, dim3(NB), dim3(256), 0, stream,
                           rbias, part, vsum, out_poses, out_act, 1);
        hipLaunchKernelGGL((caps_votes<true, 2>), vgrid, vblk, 0, stream,
                           poses, weight, wsA, wsB, vsum, part, out_coup);
        hipLaunchKernelGGL(caps_squash, dim3(NB), dim3(256), 0, stream,
                           rbias, part, vsum, out_poses, out_act, 2);
    } else {
        hipLaunchKernelGGL((caps_votes<false, 0>), vgrid, vblk, 0, stream,
                           poses, weight, wsA, wsB, vsum, part, out_coup);
        hipLaunchKernelGGL(caps_squash, dim3(NB), dim3(256), 0, stream,
                           rbias, part, vsum, out_poses, out_act, 0);
        hipLaunchKernelGGL((caps_votes<false, 1>), vgrid, vblk, 0, stream,
                           poses, weight, wsA, wsB, vsum, part, out_coup);
        hipLaunchKernelGGL(caps_squash, dim3(NB), dim3(256), 0, stream,
                           rbias, part, vsum, out_poses, out_act, 1);
        hipLaunchKernelGGL((caps_votes<false, 2>), vgrid, vblk, 0, stream,
                           poses, weight, wsA, wsB, vsum, part, out_coup);
        hipLaunchKernelGGL(caps_squash, dim3(NB), dim3(256), 0, stream,
                           rbias, part, vsum, out_poses, out_act, 2);
    }
}

// Round 7
// 384.603 us; speedup vs baseline: 1.0420x; 1.0420x over previous
//
#include <hip/hip_runtime.h>

// CapsClass2d dynamic routing — K=16 MFMA, spill-free launch bounds, bt-loop.
// b=256, P=1152, C=10, os=is=16, 3 iterations.
// logits telescope: logits_k = dot(sum_{j<k} v_j, votes) -> only vsum state.
//
// R5/R6 lesson: __launch_bounds__(256,4) capped VGPR+AGPR at 128 < ~144 live
// (acc[10]+sacc[10] floatx4 = 80 acc regs) -> scratch spill ~100MB/dispatch
// both directions (the mystery FETCH 98 / WRITE 119 MB). Fix: (256,3) = 168.
// Also: BTL=2 batch-tiles per block so A-frags re-used block-locally (L1),
// grid (72,8): all btg-blocks of an x-chunk land on one XCD (72 % 8 == 0).
//
// votes[p] = W_p[160x16] @ X_p[16x256] via mfma_f32_16x16x16_bf16:
//   A[m=o][k]: m=lane&15, k=(lane>>4)*4+j ; B[k][n=b]: n=lane&15
//   C/D: col(b)=lane&15, row(o)=(lane>>4)*4+reg
// it=0: coup==0.1 exactly -> MFMA accumulator chains over p, scaled 0.1 at end.

#define NPOS 1152
#define NC 10
#define IS 16
#define NB 256
#define CO 160
#define CAPS_EPS 1e-8f
#define PW 4                        // positions per wave
#define XCH 72                      // x-chunks (16 positions each)
#define BTL 2                       // b-tiles per block
#define NBTG 8                      // gridDim.y
#define NA_SLOTS (NPOS * NC * 64)   // 737280 uint2 A-frag slots (5.9 MB)
#define VS_STRIDE 164
#define SM_STRIDE 161
#define PARTREG (16 * CO)           // 2560 floats per (x,bt) partial region

typedef __attribute__((ext_vector_type(4))) short bf16x4;
typedef __attribute__((ext_vector_type(8))) short bf16x8;
typedef __attribute__((ext_vector_type(4))) float floatx4;

#if defined(__has_builtin)
#  if __has_builtin(__builtin_amdgcn_mfma_f32_16x16x16bf16_1k)
#    define HAVE_MFMA16 1
#  endif
#endif

__device__ __forceinline__ unsigned f2bf(float x) {
    union { float f; unsigned u; } v; v.f = x;
    return (v.u + 0x7FFFu + ((v.u >> 16) & 1u)) >> 16;
}
__device__ __forceinline__ uint2 pack4(float4 a) {
    uint2 r;
    r.x = f2bf(a.x) | (f2bf(a.y) << 16);
    r.y = f2bf(a.z) | (f2bf(a.w) << 16);
    return r;
}

// Pre-convert W into bf16 K=16 fragment layout (uint2 per lane).
__global__ __launch_bounds__(256) void preconv_kernel(
    const float* __restrict__ weight, uint2* __restrict__ wsA)
{
    const int gid = blockIdx.x * 256 + threadIdx.x;
    if (gid >= NA_SLOTS) return;
    const int L = gid & 63, pc = gid >> 6;            // pc = p*10+c
    const int o = L & 15, q = L >> 4;
    const float4 w = *(const float4*)(weight + (size_t)pc * 256 + o * 16 + q * 4);
    wsA[gid] = pack4(w);
}

#ifdef HAVE_MFMA16
typedef bf16x4 FragT;
#define MFMA_OP(a, b, c) __builtin_amdgcn_mfma_f32_16x16x16bf16_1k(a, b, c, 0, 0, 0)

__device__ __forceinline__ FragT u2frag(uint2 u) {
    union { uint2 u; FragT f; } c; c.u = u; return c.f;
}
template <bool PC>
__device__ __forceinline__ FragT loadA(const uint2* wsA, const float* weight,
                                       int p, int c, int lane) {
    if (PC) return u2frag(wsA[((size_t)p * NC + c) * 64 + lane]);
    const int o = lane & 15, q = lane >> 4;
    const float4 w = *(const float4*)(weight + ((size_t)p * NC + c) * 256 + o * 16 + q * 4);
    return u2frag(pack4(w));
}
__device__ __forceinline__ FragT loadB(const float* poses, int p, int b0, int lane) {
    const int bl = lane & 15, q = lane >> 4;
    const float4 x = *(const float4*)(poses + ((size_t)(b0 + bl) * NPOS + p) * IS + q * 4);
    return u2frag(pack4(x));
}
#else
// Fallback: K=32 MFMA, upper quads zero.
typedef bf16x8 FragT;
#define MFMA_OP(a, b, c) __builtin_amdgcn_mfma_f32_16x16x32_bf16(a, b, c, 0, 0, 0)

template <bool PC>
__device__ __forceinline__ FragT loadA(const uint2* wsA, const float* weight,
                                       int p, int c, int lane) {
    union { unsigned u[4]; FragT f; } r;
    const bool act = lane < 32;
    const int o = lane & 15, q = (lane >> 4) & 1;
    if (PC) {
        const uint2* base = wsA + ((size_t)p * NC + c) * 64 + q * 32 + o;
        const uint2 lo = base[0], hi = base[16];
        r.u[0] = act ? lo.x : 0u; r.u[1] = act ? lo.y : 0u;
        r.u[2] = act ? hi.x : 0u; r.u[3] = act ? hi.y : 0u;
    } else {
        const float4* s = (const float4*)(weight + ((size_t)p * NC + c) * 256 + o * 16 + q * 8);
        const uint2 lo = pack4(s[0]), hi = pack4(s[1]);
        r.u[0] = act ? lo.x : 0u; r.u[1] = act ? lo.y : 0u;
        r.u[2] = act ? hi.x : 0u; r.u[3] = act ? hi.y : 0u;
    }
    return r.f;
}
__device__ __forceinline__ FragT loadB(const float* poses, int p, int b0, int lane) {
    union { unsigned u[4]; FragT f; } r;
    const bool act = lane < 32;
    const int bl = lane & 15, q = (lane >> 4) & 1;
    const float4* s = (const float4*)(poses + ((size_t)(b0 + bl) * NPOS + p) * IS + q * 8);
    const uint2 lo = pack4(s[0]), hi = pack4(s[1]);
    r.u[0] = act ? lo.x : 0u; r.u[1] = act ? lo.y : 0u;
    r.u[2] = act ? hi.x : 0u; r.u[3] = act ? hi.y : 0u;
    return r.f;
}
#endif

template <bool PC, int MODE>   // MODE: 0 = it0, 1 = it1, 2 = it2 (writes coup)
__global__ __launch_bounds__(256, 3) void caps_votes(
    const float* __restrict__ poses, const float* __restrict__ weight,
    const uint2* __restrict__ wsA, const float* __restrict__ vsum,
    float* __restrict__ part, float* __restrict__ out_coup)
{
    const int t    = threadIdx.x;
    const int wave = t >> 6, lane = t & 63;
    const int bcol = lane & 15, quad = lane >> 4;
    const int xc   = blockIdx.x;
    const int bt0  = blockIdx.y * BTL;
    const int pbase = xc * 16 + wave * PW;

    __shared__ float sh_vsum[BTL * 16 * VS_STRIDE];   // 21 KB
    __shared__ float s_merge[16 * SM_STRIDE];         // 10.3 KB

    if (MODE > 0) {
        for (int k = t; k < BTL * 16 * CO; k += 256) {
            const int bb = k / CO, j = k - bb * CO;
            sh_vsum[bb * VS_STRIDE + j] = vsum[(size_t)(bt0 * 16 + bb) * CO + j];
        }
    }

    for (int btl = 0; btl < BTL; ++btl) {
        const int bt = bt0 + btl, b0 = bt * 16;
        __syncthreads();                               // prev btl store done / vsum visible
        for (int k = t; k < 16 * SM_STRIDE; k += 256) s_merge[k] = 0.f;
        __syncthreads();

        floatx4 sacc[NC];
#pragma unroll
        for (int c = 0; c < NC; ++c) sacc[c] = (floatx4)(0.f);

        for (int pi = 0; pi < PW; ++pi) {
            const int p = pbase + pi;
            const FragT bf = loadB(poses, p, b0, lane);

            if (MODE == 0) {
                // coup == 0.1 exactly -> accumulate votes in MFMA C, scale later
#pragma unroll
                for (int c = 0; c < NC; ++c)
                    sacc[c] = MFMA_OP(loadA<PC>(wsA, weight, p, c, lane), bf, sacc[c]);
            } else {
                floatx4 acc[NC];
#pragma unroll
                for (int c = 0; c < NC; ++c)
                    acc[c] = MFMA_OP(loadA<PC>(wsA, weight, p, c, lane), bf, (floatx4)(0.f));

                float lg[NC];
                float mx = -1e30f;
#pragma unroll
                for (int c = 0; c < NC; ++c) {
                    const float4 vv = *(const float4*)
                        &sh_vsum[(btl * 16 + bcol) * VS_STRIDE + c * 16 + quad * 4];
                    float pt = vv.x * acc[c][0] + vv.y * acc[c][1]
                             + vv.z * acc[c][2] + vv.w * acc[c][3];
                    pt += __shfl_xor(pt, 16);
                    pt += __shfl_xor(pt, 32);
                    lg[c] = pt;
                    mx = fmaxf(mx, pt);
                }
                float coup[NC], sum = 0.f;
#pragma unroll
                for (int c = 0; c < NC; ++c) { coup[c] = __expf(lg[c] - mx); sum += coup[c]; }
                const float inv = 1.f / sum;
#pragma unroll
                for (int c = 0; c < NC; ++c) coup[c] *= inv;

                if (MODE == 2 && quad == 0) {
                    float* cp = out_coup + (size_t)(b0 + bcol) * (NC * NPOS) + p;
#pragma unroll
                    for (int c = 0; c < NC; ++c) cp[c * NPOS] = coup[c];
                }

#pragma unroll
                for (int c = 0; c < NC; ++c)
#pragma unroll
                    for (int r = 0; r < 4; ++r) sacc[c][r] += coup[c] * acc[c][r];
            }
        }

        // merge the block's 4 waves in LDS, plain store to private partial
        const float scale = (MODE == 0) ? 0.1f : 1.f;
#pragma unroll
        for (int c = 0; c < NC; ++c)
#pragma unroll
            for (int r = 0; r < 4; ++r)
                atomicAdd(&s_merge[bcol * SM_STRIDE + c * 16 + quad * 4 + r],
                          scale * sacc[c][r]);
        __syncthreads();
        float* dst = part + ((size_t)xc * 16 + bt) * PARTREG;
        for (int k = t; k < PARTREG; k += 256) {
            const int b = k / CO, j = k - b * CO;
            dst[k] = s_merge[b * SM_STRIDE + j];
        }
    }
}

// Sum the 72 chunk-partials, add bias, squash, update vsum / outputs.
__global__ __launch_bounds__(256) void caps_squash(
    const float* __restrict__ rbias,   // [10, 16]
    const float* __restrict__ part,    // [72][16][16*160]
    float* __restrict__ vsum,          // [256, 10, 16]
    float* __restrict__ out_poses,     // [256, 10, 16]
    float* __restrict__ out_act,       // [256, 10]
    int it)
{
    const int b = blockIdx.x;          // 0..255
    const int t = threadIdx.x;
    if (t >= CO) return;
    const int c = t >> 4;
    const int bt = b >> 4, bl = b & 15;

    float s = rbias[t];
    const float* src = part + (size_t)bt * PARTREG + bl * CO + t;
#pragma unroll 8
    for (int pc = 0; pc < XCH; ++pc)
        s += src[(size_t)pc * 16 * PARTREG];

    float sq = s * s;
    sq += __shfl_xor(sq, 1);
    sq += __shfl_xor(sq, 2);
    sq += __shfl_xor(sq, 4);
    sq += __shfl_xor(sq, 8);
    const float f = (sq / (1.f + sq)) * rsqrtf(sq + CAPS_EPS);
    const float v = f * s;

    const size_t idx = (size_t)b * CO + t;
    if (it == 0) {
        vsum[idx] = v;                 // first write — no memset needed
    } else if (it == 1) {
        vsum[idx] += v;
    } else {
        out_poses[idx] = v;
        if ((t & 15) == 0) out_act[(size_t)b * NC + c] = sqrtf(f * f * sq + CAPS_EPS);
    }
}

extern "C" void kernel_launch(void* const* d_in, const int* in_sizes, int n_in,
                              void* d_out, int out_size, void* d_ws, size_t ws_size,
                              hipStream_t stream) {
    const float* poses  = (const float*)d_in[0];
    // d_in[1] (input_caps_activations) unused by the reference computation.
    const float* weight = (const float*)d_in[2];
    const float* rbias  = (const float*)d_in[3];

    float* out       = (float*)d_out;
    float* out_poses = out;                                   // 256*10*16
    float* out_act   = out + (size_t)NB * CO;                 // 256*10
    float* out_coup  = out_act + (size_t)NB * NC;             // 256*10*1152

    float* vsum = (float*)d_ws;                               // 256*160 floats
    float* part = vsum + (size_t)NB * CO;                     // 72*16*2560 floats
    uint2* wsA  = (uint2*)(part + (size_t)XCH * 16 * PARTREG);

    const size_t need = (size_t)NB * CO * sizeof(float)
                      + (size_t)XCH * 16 * PARTREG * sizeof(float)
                      + (size_t)NA_SLOTS * sizeof(uint2);     // ~17.9 MB
    const bool pc = (ws_size >= need);

    const dim3 vgrid(XCH, NBTG), vblk(256);
    if (pc) {
        hipLaunchKernelGGL(preconv_kernel, dim3(NA_SLOTS / 256), dim3(256), 0, stream,
                           weight, wsA);
        hipLaunchKernelGGL((caps_votes<true, 0>), vgrid, vblk, 0, stream,
                           poses, weight, wsA, vsum, part, out_coup);
        hipLaunchKernelGGL(caps_squash, dim3(NB), dim3(256), 0, stream,
                           rbias, part, vsum, out_poses, out_act, 0);
        hipLaunchKernelGGL((caps_votes<true, 1>), vgrid, vblk, 0, stream,
                           poses, weight, wsA, vsum, part, out_coup);
        hipLaunchKernelGGL(caps_squash, dim3(NB), dim3(256), 0, stream,
                           rbias, part, vsum, out_poses, out_act, 1);
        hipLaunchKernelGGL((caps_votes<true, 2>), vgrid, vblk, 0, stream,
                           poses, weight, wsA, vsum, part, out_coup);
        hipLaunchKernelGGL(caps_squash, dim3(NB), dim3(256), 0, stream,
                           rbias, part, vsum, out_poses, out_act, 2);
    } else {
        hipLaunchKernelGGL((caps_votes<false, 0>), vgrid, vblk, 0, stream,
                           poses, weight, wsA, vsum, part, out_coup);
        hipLaunchKernelGGL(caps_squash, dim3(NB), dim3(256), 0, stream,
                           rbias, part, vsum, out_poses, out_act, 0);
        hipLaunchKernelGGL((caps_votes<false, 1>), vgrid, vblk, 0, stream,
                           poses, weight, wsA, vsum, part, out_coup);
        hipLaunchKernelGGL(caps_squash, dim3(NB), dim3(256), 0, stream,
                           rbias, part, vsum, out_poses, out_act, 1);
        hipLaunchKernelGGL((caps_votes<false, 2>), vgrid, vblk, 0, stream,
                           poses, weight, wsA, vsum, part, out_coup);
        hipLaunchKernelGGL(caps_squash, dim3(NB), dim3(256), 0, stream,
                           rbias, part, vsum, out_poses, out_act, 2);
    }
}

// Round 8
// 370.549 us; speedup vs baseline: 1.0815x; 1.0379x over previous
//
#include <hip/hip_runtime.h>

// CapsClass2d dynamic routing — K=16 MFMA, two-pass c-loop (minimal live set).
// b=256, P=1152, C=10, os=is=16, 3 iterations.
// logits telescope: logits_k = dot(sum_{j<k} v_j, votes) -> only vsum state.
//
// R4-R7 lesson: acc[10]+sacc[10] (80 accumulator regs) kept every variant at
// or over the VGPR+AGPR cap -> scratch spill + register-starved scheduling.
// R8: pass1 computes logits with ONE transient acc (recomputed per c), pass2
// re-runs the MFMA (MfmaUtil is 1% — free) and folds coup*acc into sacc.
// Live ~70 regs < (256,3)=170 cap -> no spill, loads can batch.
//
// votes[p] = W_p[160x16] @ X_p[16x256] via mfma_f32_16x16x16_bf16:
//   A[m=o][k]: m=lane&15, k=(lane>>4)*4+j ; B[k][n=b]: n=lane&15
//   C/D: col(b)=lane&15, row(o)=(lane>>4)*4+reg
// Grid (72,16) = 1152 blocks = 4.5/CU. it=0: coup==0.1 -> MFMA-chain kernel.

#define NPOS 1152
#define NC 10
#define IS 16
#define NB 256
#define CO 160
#define CAPS_EPS 1e-8f
#define PW 4                        // positions per wave
#define XCH 72                      // x-chunks (16 positions each)
#define NA_SLOTS (NPOS * NC * 64)   // 737280 uint2 A-frag slots (5.9 MB)
#define VS_STRIDE 164
#define SM_STRIDE 161
#define PARTREG (16 * CO)           // 2560 floats per (x,bt) partial region

typedef __attribute__((ext_vector_type(4))) short bf16x4;
typedef __attribute__((ext_vector_type(8))) short bf16x8;
typedef __attribute__((ext_vector_type(4))) float floatx4;

#if defined(__has_builtin)
#  if __has_builtin(__builtin_amdgcn_mfma_f32_16x16x16bf16_1k)
#    define HAVE_MFMA16 1
#  endif
#endif

__device__ __forceinline__ unsigned f2bf(float x) {
    union { float f; unsigned u; } v; v.f = x;
    return (v.u + 0x7FFFu + ((v.u >> 16) & 1u)) >> 16;
}
__device__ __forceinline__ uint2 pack4(float4 a) {
    uint2 r;
    r.x = f2bf(a.x) | (f2bf(a.y) << 16);
    r.y = f2bf(a.z) | (f2bf(a.w) << 16);
    return r;
}

__global__ __launch_bounds__(256) void preconv_kernel(
    const float* __restrict__ weight, uint2* __restrict__ wsA)
{
    const int gid = blockIdx.x * 256 + threadIdx.x;
    if (gid >= NA_SLOTS) return;
    const int L = gid & 63, pc = gid >> 6;            // pc = p*10+c
    const int o = L & 15, q = L >> 4;
    const float4 w = *(const float4*)(weight + (size_t)pc * 256 + o * 16 + q * 4);
    wsA[gid] = pack4(w);
}

#ifdef HAVE_MFMA16
typedef bf16x4 FragT;
#define MFMA_OP(a, b, c) __builtin_amdgcn_mfma_f32_16x16x16bf16_1k(a, b, c, 0, 0, 0)

__device__ __forceinline__ FragT u2frag(uint2 u) {
    union { uint2 u; FragT f; } c; c.u = u; return c.f;
}
template <bool PC>
__device__ __forceinline__ FragT loadA(const uint2* wsA, const float* weight,
                                       int p, int c, int lane) {
    if (PC) return u2frag(wsA[((size_t)p * NC + c) * 64 + lane]);
    const int o = lane & 15, q = lane >> 4;
    const float4 w = *(const float4*)(weight + ((size_t)p * NC + c) * 256 + o * 16 + q * 4);
    return u2frag(pack4(w));
}
__device__ __forceinline__ FragT loadB(const float* poses, int p, int b0, int lane) {
    const int bl = lane & 15, q = lane >> 4;
    const float4 x = *(const float4*)(poses + ((size_t)(b0 + bl) * NPOS + p) * IS + q * 4);
    return u2frag(pack4(x));
}
#else
typedef bf16x8 FragT;
#define MFMA_OP(a, b, c) __builtin_amdgcn_mfma_f32_16x16x32_bf16(a, b, c, 0, 0, 0)

template <bool PC>
__device__ __forceinline__ FragT loadA(const uint2* wsA, const float* weight,
                                       int p, int c, int lane) {
    union { unsigned u[4]; FragT f; } r;
    const bool act = lane < 32;
    const int o = lane & 15, q = (lane >> 4) & 1;
    if (PC) {
        const uint2* base = wsA + ((size_t)p * NC + c) * 64 + q * 32 + o;
        const uint2 lo = base[0], hi = base[16];
        r.u[0] = act ? lo.x : 0u; r.u[1] = act ? lo.y : 0u;
        r.u[2] = act ? hi.x : 0u; r.u[3] = act ? hi.y : 0u;
    } else {
        const float4* s = (const float4*)(weight + ((size_t)p * NC + c) * 256 + o * 16 + q * 8);
        const uint2 lo = pack4(s[0]), hi = pack4(s[1]);
        r.u[0] = act ? lo.x : 0u; r.u[1] = act ? lo.y : 0u;
        r.u[2] = act ? hi.x : 0u; r.u[3] = act ? hi.y : 0u;
    }
    return r.f;
}
__device__ __forceinline__ FragT loadB(const float* poses, int p, int b0, int lane) {
    union { unsigned u[4]; FragT f; } r;
    const bool act = lane < 32;
    const int bl = lane & 15, q = (lane >> 4) & 1;
    const float4* s = (const float4*)(poses + ((size_t)(b0 + bl) * NPOS + p) * IS + q * 8);
    const uint2 lo = pack4(s[0]), hi = pack4(s[1]);
    r.u[0] = act ? lo.x : 0u; r.u[1] = act ? lo.y : 0u;
    r.u[2] = act ? hi.x : 0u; r.u[3] = act ? hi.y : 0u;
    return r.f;
}
#endif

// ---------- it0: coup == 0.1 exactly, pure MFMA-accumulate ----------
template <bool PC>
__global__ __launch_bounds__(256, 3) void caps_votes0(
    const float* __restrict__ poses, const float* __restrict__ weight,
    const uint2* __restrict__ wsA, float* __restrict__ part)
{
    const int t    = threadIdx.x;
    const int wave = t >> 6, lane = t & 63;
    const int bcol = lane & 15, quad = lane >> 4;
    const int xc   = blockIdx.x;
    const int bt   = blockIdx.y, b0 = bt * 16;
    const int pbase = xc * 16 + wave * PW;

    __shared__ float s_merge[16 * SM_STRIDE];
    for (int k = t; k < 16 * SM_STRIDE; k += 256) s_merge[k] = 0.f;
    __syncthreads();

    floatx4 sacc[NC];
#pragma unroll
    for (int c = 0; c < NC; ++c) sacc[c] = (floatx4)(0.f);

    for (int pi = 0; pi < PW; ++pi) {
        const int p = pbase + pi;
        const FragT bf = loadB(poses, p, b0, lane);
#pragma unroll
        for (int c = 0; c < NC; ++c)
            sacc[c] = MFMA_OP(loadA<PC>(wsA, weight, p, c, lane), bf, sacc[c]);
    }

#pragma unroll
    for (int c = 0; c < NC; ++c)
#pragma unroll
        for (int r = 0; r < 4; ++r)
            atomicAdd(&s_merge[bcol * SM_STRIDE + c * 16 + quad * 4 + r],
                      0.1f * sacc[c][r]);
    __syncthreads();
    float* dst = part + ((size_t)xc * 16 + bt) * PARTREG;
    for (int k = t; k < PARTREG; k += 256) {
        const int b = k / CO, j = k - b * CO;
        dst[k] = s_merge[b * SM_STRIDE + j];
    }
}

// ---------- it1/it2: two-pass c-loop, minimal live registers ----------
template <bool PC, bool WC>
__global__ __launch_bounds__(256, 3) void caps_votes12(
    const float* __restrict__ poses, const float* __restrict__ weight,
    const uint2* __restrict__ wsA, const float* __restrict__ vsum,
    float* __restrict__ part, float* __restrict__ out_coup)
{
    const int t    = threadIdx.x;
    const int wave = t >> 6, lane = t & 63;
    const int bcol = lane & 15, quad = lane >> 4;
    const int xc   = blockIdx.x;
    const int bt   = blockIdx.y, b0 = bt * 16;
    const int pbase = xc * 16 + wave * PW;

    __shared__ float sh_vsum[16 * VS_STRIDE];
    __shared__ float s_merge[16 * SM_STRIDE];
    for (int k = t; k < 16 * SM_STRIDE; k += 256) s_merge[k] = 0.f;
    for (int k = t; k < 16 * CO; k += 256) {
        const int b = k / CO, j = k - b * CO;
        sh_vsum[b * VS_STRIDE + j] = vsum[(size_t)(b0 + b) * CO + j];
    }
    __syncthreads();

    floatx4 sacc[NC];
#pragma unroll
    for (int c = 0; c < NC; ++c) sacc[c] = (floatx4)(0.f);

    for (int pi = 0; pi < PW; ++pi) {
        const int p = pbase + pi;
        const FragT bf = loadB(poses, p, b0, lane);

        // pass 1: logits only — ONE transient acc at a time
        float lg[NC];
#pragma unroll
        for (int c = 0; c < NC; ++c) {
            const floatx4 acc = MFMA_OP(loadA<PC>(wsA, weight, p, c, lane), bf, (floatx4)(0.f));
            const float4 vv = *(const float4*)&sh_vsum[bcol * VS_STRIDE + c * 16 + quad * 4];
            float pt = vv.x * acc[0] + vv.y * acc[1] + vv.z * acc[2] + vv.w * acc[3];
            pt += __shfl_xor(pt, 16);
            pt += __shfl_xor(pt, 32);
            lg[c] = pt;
        }
        float mx = lg[0];
#pragma unroll
        for (int c = 1; c < NC; ++c) mx = fmaxf(mx, lg[c]);
        float coup[NC], sum = 0.f;
#pragma unroll
        for (int c = 0; c < NC; ++c) { coup[c] = __expf(lg[c] - mx); sum += coup[c]; }
        const float inv = 1.f / sum;
#pragma unroll
        for (int c = 0; c < NC; ++c) coup[c] *= inv;

        if (WC && quad == 0) {
            float* cp = out_coup + (size_t)(b0 + bcol) * (NC * NPOS) + p;
#pragma unroll
            for (int c = 0; c < NC; ++c) cp[c * NPOS] = coup[c];
        }

        // pass 2: recompute acc per c (MFMA is ~free), fold into sacc
#pragma unroll
        for (int c = 0; c < NC; ++c) {
            const floatx4 acc = MFMA_OP(loadA<PC>(wsA, weight, p, c, lane), bf, (floatx4)(0.f));
#pragma unroll
            for (int r = 0; r < 4; ++r) sacc[c][r] += coup[c] * acc[r];
        }
    }

#pragma unroll
    for (int c = 0; c < NC; ++c)
#pragma unroll
        for (int r = 0; r < 4; ++r)
            atomicAdd(&s_merge[bcol * SM_STRIDE + c * 16 + quad * 4 + r], sacc[c][r]);
    __syncthreads();
    float* dst = part + ((size_t)xc * 16 + bt) * PARTREG;
    for (int k = t; k < PARTREG; k += 256) {
        const int b = k / CO, j = k - b * CO;
        dst[k] = s_merge[b * SM_STRIDE + j];
    }
}

// Sum the 72 chunk-partials, add bias, squash, update vsum / outputs.
__global__ __launch_bounds__(256) void caps_squash(
    const float* __restrict__ rbias,   // [10, 16]
    const float* __restrict__ part,    // [72][16][16*160]
    float* __restrict__ vsum,          // [256, 10, 16]
    float* __restrict__ out_poses,     // [256, 10, 16]
    float* __restrict__ out_act,       // [256, 10]
    int it)
{
    const int b = blockIdx.x;          // 0..255
    const int t = threadIdx.x;
    if (t >= CO) return;
    const int c = t >> 4;
    const int bt = b >> 4, bl = b & 15;

    float s = rbias[t];
    const float* src = part + (size_t)bt * PARTREG + bl * CO + t;
#pragma unroll 8
    for (int pc = 0; pc < XCH; ++pc)
        s += src[(size_t)pc * 16 * PARTREG];

    float sq = s * s;
    sq += __shfl_xor(sq, 1);
    sq += __shfl_xor(sq, 2);
    sq += __shfl_xor(sq, 4);
    sq += __shfl_xor(sq, 8);
    const float f = (sq / (1.f + sq)) * rsqrtf(sq + CAPS_EPS);
    const float v = f * s;

    const size_t idx = (size_t)b * CO + t;
    if (it == 0) {
        vsum[idx] = v;                 // first write — no memset needed
    } else if (it == 1) {
        vsum[idx] += v;
    } else {
        out_poses[idx] = v;
        if ((t & 15) == 0) out_act[(size_t)b * NC + c] = sqrtf(f * f * sq + CAPS_EPS);
    }
}

extern "C" void kernel_launch(void* const* d_in, const int* in_sizes, int n_in,
                              void* d_out, int out_size, void* d_ws, size_t ws_size,
                              hipStream_t stream) {
    const float* poses  = (const float*)d_in[0];
    // d_in[1] (input_caps_activations) unused by the reference computation.
    const float* weight = (const float*)d_in[2];
    const float* rbias  = (const float*)d_in[3];

    float* out       = (float*)d_out;
    float* out_poses = out;                                   // 256*10*16
    float* out_act   = out + (size_t)NB * CO;                 // 256*10
    float* out_coup  = out_act + (size_t)NB * NC;             // 256*10*1152

    float* vsum = (float*)d_ws;                               // 256*160 floats
    float* part = vsum + (size_t)NB * CO;                     // 72*16*2560 floats
    uint2* wsA  = (uint2*)(part + (size_t)XCH * 16 * PARTREG);

    const size_t need = (size_t)NB * CO * sizeof(float)
                      + (size_t)XCH * 16 * PARTREG * sizeof(float)
                      + (size_t)NA_SLOTS * sizeof(uint2);     // ~17.9 MB
    const bool pc = (ws_size >= need);

    const dim3 vgrid(XCH, 16), vblk(256);
    if (pc) {
        hipLaunchKernelGGL(preconv_kernel, dim3(NA_SLOTS / 256), dim3(256), 0, stream,
                           weight, wsA);
        hipLaunchKernelGGL((caps_votes0<true>), vgrid, vblk, 0, stream,
                           poses, weight, wsA, part);
        hipLaunchKernelGGL(caps_squash, dim3(NB), dim3(256), 0, stream,
                           rbias, part, vsum, out_poses, out_act, 0);
        hipLaunchKernelGGL((caps_votes12<true, false>), vgrid, vblk, 0, stream,
                           poses, weight, wsA, vsum, part, out_coup);
        hipLaunchKernelGGL(caps_squash, dim3(NB), dim3(256), 0, stream,
                           rbias, part, vsum, out_poses, out_act, 1);
        hipLaunchKernelGGL((caps_votes12<true, true>), vgrid, vblk, 0, stream,
                           poses, weight, wsA, vsum, part, out_coup);
        hipLaunchKernelGGL(caps_squash, dim3(NB), dim3(256), 0, stream,
                           rbias, part, vsum, out_poses, out_act, 2);
    } else {
        hipLaunchKernelGGL((caps_votes0<false>), vgrid, vblk, 0, stream,
                           poses, weight, wsA, part);
        hipLaunchKernelGGL(caps_squash, dim3(NB), dim3(256), 0, stream,
                           rbias, part, vsum, out_poses, out_act, 0);
        hipLaunchKernelGGL((caps_votes12<false, false>), vgrid, vblk, 0, stream,
                           poses, weight, wsA, vsum, part, out_coup);
        hipLaunchKernelGGL(caps_squash, dim3(NB), dim3(256), 0, stream,
                           rbias, part, vsum, out_poses, out_act, 1);
        hipLaunchKernelGGL((caps_votes12<false, true>), vgrid, vblk, 0, stream,
                           poses, weight, wsA, vsum, part, out_coup);
        hipLaunchKernelGGL(caps_squash, dim3(NB), dim3(256), 0, stream,
                           rbias, part, vsum, out_poses, out_act, 2);
    }
}

// Round 9
// 341.779 us; speedup vs baseline: 1.1725x; 1.0842x over previous
//
#include <hip/hip_runtime.h>

// CapsClass2d dynamic routing — R9: register-headroom + batched frag loads.
// b=256, P=1152, C=10, os=is=16, 3 iterations.
// logits telescope: logits_k = dot(sum_{j<k} v_j, votes) -> only vsum state.
//
// R4-R8 synthesis: the hidden variable was the register budget. Tight caps
// spilled (R5/R6: ~100MB phantom traffic); loose code let the compiler pick
// VGPR=60 and serialize the 10 load->MFMA chains at L2 latency. R9: bounds
// (256,2) (cap ~256), vsum in regs, A/B frags staged to explicit arrays
// before MFMAs (11 loads in flight), contiguous preconverted B (no gather),
// one-pass c-loop, coup staged via LDS for coalesced stores.

#define NPOS 1152
#define NC 10
#define IS 16
#define NB 256
#define CO 160
#define CAPS_EPS 1e-8f
#define PW 4                        // positions per wave
#define XCH 72                      // x-chunks (16 positions each)
#define NA_SLOTS (NPOS * NC * 64)   // 737280 uint2 A-frag slots (5.9 MB)
#define NBS_SLOTS (NPOS * 16 * 64)  // 1179648 uint2 B-frag slots (9.4 MB)
#define SM_STRIDE 161
#define PARTREG (16 * CO)           // 2560 floats per (x,bt) partial region

typedef __attribute__((ext_vector_type(4))) short bf16x4;
typedef __attribute__((ext_vector_type(8))) short bf16x8;
typedef __attribute__((ext_vector_type(4))) float floatx4;

#if defined(__has_builtin)
#  if __has_builtin(__builtin_amdgcn_mfma_f32_16x16x16bf16_1k)
#    define HAVE_MFMA16 1
#  endif
#endif

__device__ __forceinline__ unsigned f2bf(float x) {
    union { float f; unsigned u; } v; v.f = x;
    return (v.u + 0x7FFFu + ((v.u >> 16) & 1u)) >> 16;
}
__device__ __forceinline__ uint2 pack4(float4 a) {
    uint2 r;
    r.x = f2bf(a.x) | (f2bf(a.y) << 16);
    r.y = f2bf(a.z) | (f2bf(a.w) << 16);
    return r;
}

// Pre-convert W (and optionally poses) into bf16 K=16 frag layout.
__global__ __launch_bounds__(256) void preconv_kernel(
    const float* __restrict__ poses, const float* __restrict__ weight,
    uint2* __restrict__ wsA, uint2* __restrict__ wsB, int doB)
{
    const int gid = blockIdx.x * 256 + threadIdx.x;
    if (gid < NA_SLOTS) {
        const int L = gid & 63, pc = gid >> 6;        // pc = p*10+c
        const int o = L & 15, q = L >> 4;
        const float4 w = *(const float4*)(weight + (size_t)pc * 256 + o * 16 + q * 4);
        wsA[gid] = pack4(w);
    } else if (doB) {
        const int s = gid - NA_SLOTS;
        if (s < NBS_SLOTS) {
            const int L = s & 63, pb = s >> 6;        // pb = p*16+bt
            const int bt = pb & 15, p = pb >> 4;
            const int bl = L & 15, q = L >> 4;
            const float4 x = *(const float4*)(poses +
                ((size_t)(bt * 16 + bl) * NPOS + p) * IS + q * 4);
            wsB[s] = pack4(x);
        }
    }
}

#ifdef HAVE_MFMA16
typedef bf16x4 FragT;
typedef uint2  ARaw;
typedef uint2  BRaw;
#define MFMA_OP(a, b, c) __builtin_amdgcn_mfma_f32_16x16x16bf16_1k(a, b, c, 0, 0, 0)

__device__ __forceinline__ FragT rawToFrag(ARaw u, int lane) {
    union { uint2 u; FragT f; } c; c.u = u; return c.f;
}
template <int WS>
__device__ __forceinline__ ARaw loadAraw(const uint2* wsA, const float* weight,
                                         int p, int c, int lane) {
    if (WS >= 1) return wsA[((size_t)p * NC + c) * 64 + lane];
    const int o = lane & 15, q = lane >> 4;
    const float4 w = *(const float4*)(weight + ((size_t)p * NC + c) * 256 + o * 16 + q * 4);
    return pack4(w);
}
template <int WS>
__device__ __forceinline__ BRaw loadBraw(const uint2* wsB, const float* poses,
                                         int p, int bt, int lane) {
    if (WS >= 2) return wsB[((size_t)p * 16 + bt) * 64 + lane];
    const int bl = lane & 15, q = lane >> 4;
    const float4 x = *(const float4*)(poses + ((size_t)(bt * 16 + bl) * NPOS + p) * IS + q * 4);
    return pack4(x);
}
#else
// Fallback: K=32 MFMA, upper half-K zeroed; raw payload = two uint2.
typedef bf16x8 FragT;
struct ARaw { uint2 lo, hi; };
typedef ARaw BRaw;
#define MFMA_OP(a, b, c) __builtin_amdgcn_mfma_f32_16x16x32_bf16(a, b, c, 0, 0, 0)

__device__ __forceinline__ FragT rawToFrag(ARaw r0, int lane) {
    union { unsigned u[4]; FragT f; } r;
    const bool act = lane < 32;
    r.u[0] = act ? r0.lo.x : 0u; r.u[1] = act ? r0.lo.y : 0u;
    r.u[2] = act ? r0.hi.x : 0u; r.u[3] = act ? r0.hi.y : 0u;
    return r.f;
}
template <int WS>
__device__ __forceinline__ ARaw loadAraw(const uint2* wsA, const float* weight,
                                         int p, int c, int lane) {
    ARaw r;
    const int o = lane & 15, q = (lane >> 4) & 1;
    if (WS >= 1) {
        const uint2* base = wsA + ((size_t)p * NC + c) * 64 + q * 32 + o;
        r.lo = base[0]; r.hi = base[16];
    } else {
        const float4* s = (const float4*)(weight + ((size_t)p * NC + c) * 256 + o * 16 + q * 8);
        r.lo = pack4(s[0]); r.hi = pack4(s[1]);
    }
    return r;
}
template <int WS>
__device__ __forceinline__ BRaw loadBraw(const uint2* wsB, const float* poses,
                                         int p, int bt, int lane) {
    BRaw r;
    const int bl = lane & 15, q = (lane >> 4) & 1;
    if (WS >= 2) {
        const uint2* base = wsB + ((size_t)p * 16 + bt) * 64 + q * 32 + bl;
        r.lo = base[0]; r.hi = base[16];
    } else {
        const float4* s = (const float4*)(poses + ((size_t)(bt * 16 + bl) * NPOS + p) * IS + q * 8);
        r.lo = pack4(s[0]); r.hi = pack4(s[1]);
    }
    return r;
}
#endif

// ---------- it0: coup == 0.1 exactly, pure MFMA-accumulate ----------
template <int WS>
__global__ __launch_bounds__(256, 4) void caps_votes0(
    const float* __restrict__ poses, const float* __restrict__ weight,
    const uint2* __restrict__ wsA, const uint2* __restrict__ wsB,
    float* __restrict__ part)
{
    const int t    = threadIdx.x;
    const int wave = t >> 6, lane = t & 63;
    const int bcol = lane & 15, quad = lane >> 4;
    const int xc   = blockIdx.x;
    const int bt   = blockIdx.y, b0 = bt * 16;
    const int pbase = xc * 16 + wave * PW;
    (void)b0;

    __shared__ float s_merge[16 * SM_STRIDE];
    for (int k = t; k < 16 * SM_STRIDE; k += 256) s_merge[k] = 0.f;
    __syncthreads();

    floatx4 sacc[NC];
#pragma unroll
    for (int c = 0; c < NC; ++c) sacc[c] = (floatx4)(0.f);

#pragma unroll
    for (int pi = 0; pi < PW; ++pi) {
        const int p = pbase + pi;
        const BRaw braw = loadBraw<WS>(wsB, poses, p, bt, lane);
        ARaw araw[NC];
#pragma unroll
        for (int c = 0; c < NC; ++c) araw[c] = loadAraw<WS>(wsA, weight, p, c, lane);
        const FragT bf = rawToFrag(braw, lane);
#pragma unroll
        for (int c = 0; c < NC; ++c)
            sacc[c] = MFMA_OP(rawToFrag(araw[c], lane), bf, sacc[c]);
    }

#pragma unroll
    for (int c = 0; c < NC; ++c)
#pragma unroll
        for (int r = 0; r < 4; ++r)
            atomicAdd(&s_merge[bcol * SM_STRIDE + c * 16 + quad * 4 + r],
                      0.1f * sacc[c][r]);
    __syncthreads();
    float* dst = part + ((size_t)xc * 16 + bt) * PARTREG;
    for (int k = t; k < PARTREG; k += 256) {
        const int b = k / CO, j = k - b * CO;
        dst[k] = s_merge[b * SM_STRIDE + j];
    }
}

// ---------- it1/it2: one-pass, vsum in regs, staged frag loads ----------
template <int WS, bool WC>
__global__ __launch_bounds__(256, 2) void caps_votes12(
    const float* __restrict__ poses, const float* __restrict__ weight,
    const uint2* __restrict__ wsA, const uint2* __restrict__ wsB,
    const float* __restrict__ vsum, float* __restrict__ part,
    float* __restrict__ out_coup)
{
    const int t    = threadIdx.x;
    const int wave = t >> 6, lane = t & 63;
    const int bcol = lane & 15, quad = lane >> 4;
    const int xc   = blockIdx.x;
    const int bt   = blockIdx.y, b0 = bt * 16;
    const int pbase = xc * 16 + wave * PW;

    __shared__ float s_merge[16 * SM_STRIDE];
    __shared__ float coup_lds[WC ? 16 * SM_STRIDE : 1];
    for (int k = t; k < 16 * SM_STRIDE; k += 256) s_merge[k] = 0.f;

    // vsum rows for this thread's batch column, in registers (40 VGPR)
    float4 vs[NC];
    {
        const float* vp = vsum + (size_t)(b0 + bcol) * CO + quad * 4;
#pragma unroll
        for (int c = 0; c < NC; ++c) vs[c] = *(const float4*)(vp + c * 16);
    }
    __syncthreads();

    floatx4 sacc[NC];
#pragma unroll
    for (int c = 0; c < NC; ++c) sacc[c] = (floatx4)(0.f);

#pragma unroll
    for (int pi = 0; pi < PW; ++pi) {
        const int p = pbase + pi;

        // stage ALL frag loads before any MFMA (11 loads in flight)
        const BRaw braw = loadBraw<WS>(wsB, poses, p, bt, lane);
        ARaw araw[NC];
#pragma unroll
        for (int c = 0; c < NC; ++c) araw[c] = loadAraw<WS>(wsA, weight, p, c, lane);

        const FragT bf = rawToFrag(braw, lane);
        floatx4 acc[NC];
#pragma unroll
        for (int c = 0; c < NC; ++c)
            acc[c] = MFMA_OP(rawToFrag(araw[c], lane), bf, (floatx4)(0.f));

        float lg[NC];
        float mx = -1e30f;
#pragma unroll
        for (int c = 0; c < NC; ++c) {
            float pt = vs[c].x * acc[c][0] + vs[c].y * acc[c][1]
                     + vs[c].z * acc[c][2] + vs[c].w * acc[c][3];
            pt += __shfl_xor(pt, 16);
            pt += __shfl_xor(pt, 32);
            lg[c] = pt;
            mx = fmaxf(mx, pt);
        }
        float coup[NC], sum = 0.f;
#pragma unroll
        for (int c = 0; c < NC; ++c) { coup[c] = __expf(lg[c] - mx); sum += coup[c]; }
        const float inv = 1.f / sum;
#pragma unroll
        for (int c = 0; c < NC; ++c) coup[c] *= inv;

        if (WC && quad == 0) {
            // park in LDS; coalesced global store in epilogue
#pragma unroll
            for (int c = 0; c < NC; ++c)
                coup_lds[bcol * SM_STRIDE + c * 16 + wave * PW + pi] = coup[c];
        }

#pragma unroll
        for (int c = 0; c < NC; ++c)
#pragma unroll
            for (int r = 0; r < 4; ++r) sacc[c][r] += coup[c] * acc[c][r];
    }

#pragma unroll
    for (int c = 0; c < NC; ++c)
#pragma unroll
        for (int r = 0; r < 4; ++r)
            atomicAdd(&s_merge[bcol * SM_STRIDE + c * 16 + quad * 4 + r], sacc[c][r]);
    __syncthreads();

    float* dst = part + ((size_t)xc * 16 + bt) * PARTREG;
    for (int k = t; k < PARTREG; k += 256) {
        const int b = k / CO, j = k - b * CO;
        dst[k] = s_merge[b * SM_STRIDE + j];
    }
    if (WC) {
        // out_coup[b][c][p]: runs of 16 consecutive p -> 64B coalesced stores
        for (int k = t; k < 16 * CO; k += 256) {
            const int b = k / CO, j = k - b * CO;
            const int c = j >> 4, pp = j & 15;
            out_coup[(size_t)(b0 + b) * (NC * NPOS) + c * NPOS + xc * 16 + pp] =
                coup_lds[b * SM_STRIDE + c * 16 + pp];
        }
    }
}

// Sum the 72 chunk-partials, add bias, squash, update vsum / outputs.
__global__ __launch_bounds__(256) void caps_squash(
    const float* __restrict__ rbias,   // [10, 16]
    const float* __restrict__ part,    // [72][16][16*160]
    float* __restrict__ vsum,          // [256, 10, 16]
    float* __restrict__ out_poses,     // [256, 10, 16]
    float* __restrict__ out_act,       // [256, 10]
    int it)
{
    const int b = blockIdx.x;          // 0..255
    const int t = threadIdx.x;
    if (t >= CO) return;
    const int c = t >> 4;
    const int bt = b >> 4, bl = b & 15;

    float s = rbias[t];
    const float* src = part + (size_t)bt * PARTREG + bl * CO + t;
#pragma unroll 8
    for (int pc = 0; pc < XCH; ++pc)
        s += src[(size_t)pc * 16 * PARTREG];

    float sq = s * s;
    sq += __shfl_xor(sq, 1);
    sq += __shfl_xor(sq, 2);
    sq += __shfl_xor(sq, 4);
    sq += __shfl_xor(sq, 8);
    const float f = (sq / (1.f + sq)) * rsqrtf(sq + CAPS_EPS);
    const float v = f * s;

    const size_t idx = (size_t)b * CO + t;
    if (it == 0) {
        vsum[idx] = v;                 // first write — no memset needed
    } else if (it == 1) {
        vsum[idx] += v;
    } else {
        out_poses[idx] = v;
        if ((t & 15) == 0) out_act[(size_t)b * NC + c] = sqrtf(f * f * sq + CAPS_EPS);
    }
}

template <int WS>
static void run_pipeline(const float* poses, const float* weight, const float* rbias,
                         const uint2* wsA, const uint2* wsB, float* vsum, float* part,
                         float* out_poses, float* out_act, float* out_coup,
                         hipStream_t stream)
{
    const dim3 vgrid(XCH, 16), vblk(256);
    hipLaunchKernelGGL((caps_votes0<WS>), vgrid, vblk, 0, stream,
                       poses, weight, wsA, wsB, part);
    hipLaunchKernelGGL(caps_squash, dim3(NB), dim3(256), 0, stream,
                       rbias, part, vsum, out_poses, out_act, 0);
    hipLaunchKernelGGL((caps_votes12<WS, false>), vgrid, vblk, 0, stream,
                       poses, weight, wsA, wsB, vsum, part, out_coup);
    hipLaunchKernelGGL(caps_squash, dim3(NB), dim3(256), 0, stream,
                       rbias, part, vsum, out_poses, out_act, 1);
    hipLaunchKernelGGL((caps_votes12<WS, true>), vgrid, vblk, 0, stream,
                       poses, weight, wsA, wsB, vsum, part, out_coup);
    hipLaunchKernelGGL(caps_squash, dim3(NB), dim3(256), 0, stream,
                       rbias, part, vsum, out_poses, out_act, 2);
}

extern "C" void kernel_launch(void* const* d_in, const int* in_sizes, int n_in,
                              void* d_out, int out_size, void* d_ws, size_t ws_size,
                              hipStream_t stream) {
    const float* poses  = (const float*)d_in[0];
    // d_in[1] (input_caps_activations) unused by the reference computation.
    const float* weight = (const float*)d_in[2];
    const float* rbias  = (const float*)d_in[3];

    float* out       = (float*)d_out;
    float* out_poses = out;                                   // 256*10*16
    float* out_act   = out + (size_t)NB * CO;                 // 256*10
    float* out_coup  = out_act + (size_t)NB * NC;             // 256*10*1152

    float* vsum = (float*)d_ws;                               // 160 KB
    float* part = vsum + (size_t)NB * CO;                     // 11.8 MB
    uint2* wsA  = (uint2*)(part + (size_t)XCH * 16 * PARTREG);
    uint2* wsB  = wsA + NA_SLOTS;

    const size_t base  = (size_t)NB * CO * sizeof(float)
                       + (size_t)XCH * 16 * PARTREG * sizeof(float);
    const size_t need1 = base + (size_t)NA_SLOTS * sizeof(uint2);               // ~17.9 MB
    const size_t need2 = need1 + (size_t)NBS_SLOTS * sizeof(uint2);             // ~27.3 MB

    if (ws_size >= need2) {
        hipLaunchKernelGGL(preconv_kernel,
                           dim3((NA_SLOTS + NBS_SLOTS + 255) / 256), dim3(256), 0, stream,
                           poses, weight, wsA, wsB, 1);
        run_pipeline<2>(poses, weight, rbias, wsA, wsB, vsum, part,
                        out_poses, out_act, out_coup, stream);
    } else if (ws_size >= need1) {
        hipLaunchKernelGGL(preconv_kernel,
                           dim3((NA_SLOTS + 255) / 256), dim3(256), 0, stream,
                           poses, weight, wsA, wsB, 0);
        run_pipeline<1>(poses, weight, rbias, wsA, wsB, vsum, part,
                        out_poses, out_act, out_coup, stream);
    } else {
        run_pipeline<0>(poses, weight, rbias, wsA, wsB, vsum, part,
                        out_poses, out_act, out_coup, stream);
    }
}